// Round 12
// baseline (681.254 us; speedup 1.0000x reference)
//
#include <hip/hip_runtime.h>
#include <math.h>

// Problem constants (fixed by reference setup_inputs)
#define NN  50000
#define EE  400000
#define DD  64
#define HH  4
#define HC  256      // H * C
#define EDD 16

__device__ __forceinline__ float gelu_exact(float x) {
    return 0.5f * x * (1.0f + erff(x * 0.70710678118654752440f));
}
// fast exp via v_exp_f32: exp(x)=2^(x*log2e). exp2(-inf)=0 preserved.
__device__ __forceinline__ float fast_exp(float x) {
    return __builtin_amdgcn_exp2f(x * 1.44269504088896340736f);
}
// f32 <-> bf16 (RNE)
__device__ __forceinline__ unsigned short f2bf(float f) {
    unsigned u = __float_as_uint(f);
    u += 0x7fffu + ((u >> 16) & 1u);
    return (unsigned short)(u >> 16);
}
__device__ __forceinline__ float bf2f(unsigned short s) {
    return __uint_as_float(((unsigned)s) << 16);
}
// order-preserving float<->uint map for atomicMax on signed floats
__device__ __forceinline__ unsigned fmapu(float f) {
    unsigned u = __float_as_uint(f);
    return (u & 0x80000000u) ? ~u : (u | 0x80000000u);
}
__device__ __forceinline__ float funmapu(unsigned u) {
    u = (u & 0x80000000u) ? (u & 0x7FFFFFFFu) : ~u;
    return __uint_as_float(u);
}
#define AMAX_INIT 0x007FFFFFu   // fmapu(-inf)

// ---------- fills ----------
__global__ void fill_u32(unsigned* __restrict__ p, unsigned v, int n) {
    int i = blockIdx.x * blockDim.x + threadIdx.x;
    int s = gridDim.x * blockDim.x;
    for (; i < n; i += s) p[i] = v;
}

// ---------- CSR build ----------
__global__ void hist_k(const int* __restrict__ ei, int* __restrict__ deg) {
    int e = blockIdx.x * 256 + threadIdx.x;
    if (e < EE) atomicAdd(&deg[ei[EE + e]], 1);
}
__global__ void scan1_k(const int* __restrict__ deg, int* __restrict__ rowptr,
                        int* __restrict__ bsum) {
    __shared__ int s[256];
    int t = threadIdx.x, i = blockIdx.x * 256 + t;
    int v = (i < NN) ? deg[i] : 0;
    s[t] = v; __syncthreads();
    for (int o = 1; o < 256; o <<= 1) {
        int u = (t >= o) ? s[t - o] : 0;
        __syncthreads();
        s[t] += u;
        __syncthreads();
    }
    if (i < NN) rowptr[i] = s[t] - v;
    if (t == 255) bsum[blockIdx.x] = s[255];
}
__global__ void scan2_k(int* __restrict__ bsum, int nb) {
    __shared__ int s[256];
    int t = threadIdx.x;
    int v = (t < nb) ? bsum[t] : 0;
    s[t] = v; __syncthreads();
    for (int o = 1; o < 256; o <<= 1) {
        int u = (t >= o) ? s[t - o] : 0;
        __syncthreads();
        s[t] += u;
        __syncthreads();
    }
    if (t < nb) bsum[t] = s[t] - v;
}
__global__ void scan3_k(int* __restrict__ rowptr, const int* __restrict__ bsum,
                        int* __restrict__ cursor) {
    int i = blockIdx.x * 256 + threadIdx.x;
    if (i < NN) {
        int r = rowptr[i] + bsum[blockIdx.x];
        rowptr[i] = r;
        cursor[i] = r;
    }
    if (i == 0) rowptr[NN] = EE;
}
__global__ void scatter_k(const int* __restrict__ ei, int* __restrict__ cursor,
                          const float* __restrict__ ea,
                          int* __restrict__ srcs, int* __restrict__ dsts,
                          float* __restrict__ ea_s) {
    int e = blockIdx.x * 256 + threadIdx.x;
    if (e >= EE) return;
    int dst = ei[EE + e];
    int pos = atomicAdd(&cursor[dst], 1);
    srcs[pos] = ei[e];
    dsts[pos] = dst;
    const float4* s4 = (const float4*)(ea + (long)e * EDD);
    float4* d4 = (float4*)(ea_s + (long)pos * EDD);
    d4[0] = s4[0]; d4[1] = s4[1]; d4[2] = s4[2]; d4[3] = s4[3];
}

// ---------- node GEMM (dual): Y{l,r}[N,256](bf16) = X[N,64] @ W{l,r} + b ----------
__global__ __launch_bounds__(256) void gemm_node2(
    const float* __restrict__ X,
    const float* __restrict__ Wl, const float* __restrict__ bl,
    const float* __restrict__ Wr, const float* __restrict__ br,
    unsigned short* __restrict__ Yl, unsigned short* __restrict__ Yr)
{
    const int col  = threadIdx.x;
    const int base = blockIdx.x * 32;
    const float* __restrict__ W = blockIdx.y ? Wr : Wl;
    const float* __restrict__ b = blockIdx.y ? br : bl;
    unsigned short* __restrict__ Y = blockIdx.y ? Yr : Yl;

    float wk[64];
#pragma unroll
    for (int k = 0; k < 64; k++) wk[k] = W[k * 256 + col];
    const float bb = b[col];

#pragma unroll 2
    for (int r = 0; r < 32; r++) {
        const int row = base + r;
        const int rr  = (row < NN) ? row : (NN - 1);
        const float* __restrict__ xrow = X + (long)rr * 64;
        float a0 = 0.f, a1 = 0.f, a2 = 0.f, a3 = 0.f;
#pragma unroll
        for (int k = 0; k < 64; k += 4) {
            a0 = fmaf(xrow[k],     wk[k],     a0);
            a1 = fmaf(xrow[k + 1], wk[k + 1], a1);
            a2 = fmaf(xrow[k + 2], wk[k + 2], a2);
            a3 = fmaf(xrow[k + 3], wk[k + 3], a3);
        }
        if (row < NN) Y[(long)row * 256 + col] = f2bf((a0 + a1) + (a2 + a3) + bb);
    }
}

// ---------- phase A: edge logits + fused segment-max ----------
// Lane layout: head h = lane>>4, channel quad (lane&15)*4. xl/xr are bf16
// (halves gather bytes — R10 showed dur == FETCH/2.1TB/s, i.e. BW-wall).
// srcs/dsts lane-preloaded per <=64-edge slice (kills s_load from the chain).
// NOTE: do NOT add manual A/B pipelining — wreg(64) + pipeline state spills
// (R9: WRITE_SIZE 9->259 MB, 116->420 us).
__global__ __launch_bounds__(256, 4) void edge_logit_k(
    const int* __restrict__ srcs, const int* __restrict__ dsts,
    const float* __restrict__ ea_s,
    const float* __restrict__ We, const float* __restrict__ att,
    const unsigned short* __restrict__ xlh, const unsigned short* __restrict__ xrh,
    float* __restrict__ alpha4, unsigned* __restrict__ amax)
{
    const int lane = threadIdx.x & 63;
    const int gc   = ((lane >> 4) << 6) + ((lane & 15) << 2);

    float wreg[EDD][4];
#pragma unroll
    for (int k = 0; k < EDD; k++) {
        const float4 w4 = *(const float4*)(We + k * HC + gc);
        wreg[k][0] = w4.x; wreg[k][1] = w4.y; wreg[k][2] = w4.z; wreg[k][3] = w4.w;
    }
#pragma unroll
    for (int k = 0; k < EDD; k++)
#pragma unroll
        for (int j = 0; j < 4; j++) asm volatile("" : "+v"(wreg[k][j]));

    const float4 a4 = *(const float4*)(att + gc);

    const int wid = blockIdx.x * 4 + (threadIdx.x >> 6);
    const int nw  = gridDim.x * 4;
    const int cpw = (EE + nw - 1) / nw;            // 49 <= 64
    const int pbeg = wid * cpw;
    const int pend = (pbeg + cpw < EE) ? (pbeg + cpw) : EE;
    if (pbeg >= pend) return;

    // preload this slice's src/dst into lanes (one coalesced load each)
    const int pl = (pbeg + lane < EE) ? (pbeg + lane) : (EE - 1);
    const int srcv = srcs[pl];
    const int dstv = dsts[pl];

    for (int p = pbeg; p < pend; p++) {
        const int off = p - pbeg;
        const int src = __builtin_amdgcn_readfirstlane(__shfl(srcv, off, 64));
        const int dst = __builtin_amdgcn_readfirstlane(__shfl(dstv, off, 64));

        float eav[EDD];
        const float* __restrict__ eap = ea_s + (long)p * EDD;
#pragma unroll
        for (int k = 0; k < EDD; k++) eav[k] = eap[k];

        const ushort4 xlu = *(const ushort4*)(xlh + (long)src * HC + gc);
        const ushort4 xru = *(const ushort4*)(xrh + (long)dst * HC + gc);

        float ez0 = 0.f, ez1 = 0.f, ez2 = 0.f, ez3 = 0.f;
#pragma unroll
        for (int k = 0; k < EDD; k++) {
            ez0 = fmaf(eav[k], wreg[k][0], ez0);
            ez1 = fmaf(eav[k], wreg[k][1], ez1);
            ez2 = fmaf(eav[k], wreg[k][2], ez2);
            ez3 = fmaf(eav[k], wreg[k][3], ez3);
        }
        float s0 = bf2f(xlu.x) + bf2f(xru.x) + ez0;
        float s1 = bf2f(xlu.y) + bf2f(xru.y) + ez1;
        float s2 = bf2f(xlu.z) + bf2f(xru.z) + ez2;
        float s3 = bf2f(xlu.w) + bf2f(xru.w) + ez3;
        s0 = (s0 > 0.f) ? s0 : 0.2f * s0;
        s1 = (s1 > 0.f) ? s1 : 0.2f * s1;
        s2 = (s2 > 0.f) ? s2 : 0.2f * s2;
        s3 = (s3 > 0.f) ? s3 : 0.2f * s3;
        float part = fmaf(s0, a4.x, fmaf(s1, a4.y, fmaf(s2, a4.z, s3 * a4.w)));
        part += __shfl_xor(part, 1, 64);
        part += __shfl_xor(part, 2, 64);
        part += __shfl_xor(part, 4, 64);
        part += __shfl_xor(part, 8, 64);

        // fused segment-max (ordered-uint map); 4 lanes, distinct addresses
        if ((lane & 15) == 0)
            atomicMax(&amax[(long)dst * HH + (lane >> 4)], fmapu(part));

        const float h0 = __shfl(part, 0, 64);
        const float h1 = __shfl(part, 16, 64);
        const float h2 = __shfl(part, 32, 64);
        const float h3 = __shfl(part, 48, 64);
        if (lane == 0) {
            float4 o; o.x = h0; o.y = h1; o.z = h2; o.w = h3;
            *(float4*)(alpha4 + (long)p * 4) = o;
        }
    }
}

// ---------- phase B: per-node softmax + aggregation + LN/GELU ----------
// Pass 1 eliminated: per-head max comes from amax (fused into phase A).
__global__ __launch_bounds__(256) void node_agg_k(
    const int* __restrict__ rowptr, const int* __restrict__ srcs,
    const float* __restrict__ alpha4, const unsigned short* __restrict__ xlh,
    const unsigned* __restrict__ amax,
    const float* __restrict__ bias, const float* __restrict__ lng,
    const float* __restrict__ lnb, const float* __restrict__ identity,
    float* __restrict__ x1out, float* __restrict__ outp, int mode)
{
    const int lane = threadIdx.x & 63;
    const int n    = blockIdx.x * 4 + (threadIdx.x >> 6);   // 12500*4 = 50000
    const int h    = lane >> 4;
    const int jj   = lane & 15;
    const int gc   = (h << 6) + (jj << 2);
    const int cb   = jj << 2;

    const int p0 = __builtin_amdgcn_readfirstlane(rowptr[n]);
    const int p1 = __builtin_amdgcn_readfirstlane(rowptr[n + 1]);

    const float mh = funmapu(amax[(long)n * HH + h]);   // per-head max

    // weights + denom + gather-aggregate
    float dsum = 0.f;
    float ac0 = 0.f, ac1 = 0.f, ac2 = 0.f, ac3 = 0.f;
    for (int b = p0; b < p1; b += 16) {
        const int p = b + jj;
        const bool v = (p < p1);
        const int pa = v ? p : (p1 - 1);
        float a = alpha4[(long)pa * 4 + h];
        if (!v) a = -INFINITY;
        const float w = fast_exp(a - mh);          // 0 for invalid lanes
        dsum += w;
        const int sv = srcs[pa];                    // lane jj's edge src
        const int cnt = ((p1 - b) < 16) ? (p1 - b) : 16;
        for (int j = 0; j < cnt; j++) {
            const int sj   = __shfl(sv, j, 64);
            const float wj = __shfl(w, (lane & 48) | j, 64);
            const ushort4 xu = *(const ushort4*)(xlh + (long)sj * HC + gc);
            ac0 = fmaf(wj, bf2f(xu.x), ac0);
            ac1 = fmaf(wj, bf2f(xu.y), ac1);
            ac2 = fmaf(wj, bf2f(xu.z), ac2);
            ac3 = fmaf(wj, bf2f(xu.w), ac3);
        }
    }
    dsum += __shfl_xor(dsum, 1, 64);
    dsum += __shfl_xor(dsum, 2, 64);
    dsum += __shfl_xor(dsum, 4, 64);
    dsum += __shfl_xor(dsum, 8, 64);

    const float inv = 1.0f / (dsum + 1e-16f);
    float v0 = ac0 * inv, v1 = ac1 * inv, v2 = ac2 * inv, v3 = ac3 * inv;

    // head mean across the 4 groups
    v0 += __shfl_xor(v0, 16, 64); v0 += __shfl_xor(v0, 32, 64);
    v1 += __shfl_xor(v1, 16, 64); v1 += __shfl_xor(v1, 32, 64);
    v2 += __shfl_xor(v2, 16, 64); v2 += __shfl_xor(v2, 32, 64);
    v3 += __shfl_xor(v3, 16, 64); v3 += __shfl_xor(v3, 32, 64);

    if (lane < 16) {   // group 0 finishes LN + GELU + store
        const float4 b4 = *(const float4*)(bias + cb);
        v0 = v0 * 0.25f + b4.x;
        v1 = v1 * 0.25f + b4.y;
        v2 = v2 * 0.25f + b4.z;
        v3 = v3 * 0.25f + b4.w;

        float s = (v0 + v1) + (v2 + v3);
        s += __shfl_xor(s, 1, 64); s += __shfl_xor(s, 2, 64);
        s += __shfl_xor(s, 4, 64); s += __shfl_xor(s, 8, 64);
        const float mu = s * (1.0f / 64.0f);
        const float d0 = v0 - mu, d1 = v1 - mu, d2 = v2 - mu, d3 = v3 - mu;
        float q = (d0 * d0 + d1 * d1) + (d2 * d2 + d3 * d3);
        q += __shfl_xor(q, 1, 64); q += __shfl_xor(q, 2, 64);
        q += __shfl_xor(q, 4, 64); q += __shfl_xor(q, 8, 64);
        const float rs = rsqrtf(q * (1.0f / 64.0f) + 1e-5f);

        const float4 g4 = *(const float4*)(lng + cb);
        const float4 c4 = *(const float4*)(lnb + cb);
        float y0 = d0 * rs * g4.x + c4.x;
        float y1 = d1 * rs * g4.y + c4.y;
        float y2 = d2 * rs * g4.z + c4.z;
        float y3 = d3 * rs * g4.w + c4.w;

        if (mode == 0) {
            float4 o;
            o.x = gelu_exact(y0); o.y = gelu_exact(y1);
            o.z = gelu_exact(y2); o.w = gelu_exact(y3);
            *(float4*)(x1out + (long)n * DD + cb) = o;
        } else {
            const float4 id = *(const float4*)(identity + (long)n * DD + cb);
            float4 o;
            o.x = gelu_exact(y0 + id.x); o.y = gelu_exact(y1 + id.y);
            o.z = gelu_exact(y2 + id.z); o.w = gelu_exact(y3 + id.w);
            *(float4*)(outp + (long)n * DD + cb) = o;
        }
    }
}

// ---------- launch ----------
extern "C" void kernel_launch(void* const* d_in, const int* in_sizes, int n_in,
                              void* d_out, int out_size, void* d_ws, size_t ws_size,
                              hipStream_t stream) {
    (void)in_sizes; (void)n_in; (void)out_size; (void)ws_size;

    const float* h     = (const float*)d_in[0];
    const int*   ei    = (const int*)d_in[1];
    const float* ea    = (const float*)d_in[2];
    const float* g1Wl  = (const float*)d_in[3];
    const float* g1bl  = (const float*)d_in[4];
    const float* g1Wr  = (const float*)d_in[5];
    const float* g1br  = (const float*)d_in[6];
    const float* g1We  = (const float*)d_in[7];
    const float* g1att = (const float*)d_in[8];
    const float* g1bias= (const float*)d_in[9];
    const float* ln1g  = (const float*)d_in[10];
    const float* ln1b  = (const float*)d_in[11];
    const float* g2Wl  = (const float*)d_in[12];
    const float* g2bl  = (const float*)d_in[13];
    const float* g2Wr  = (const float*)d_in[14];
    const float* g2br  = (const float*)d_in[15];
    const float* g2We  = (const float*)d_in[16];
    const float* g2att = (const float*)d_in[17];
    const float* g2bias= (const float*)d_in[18];
    const float* ln2g  = (const float*)d_in[19];
    const float* ln2b  = (const float*)d_in[20];

    float* out = (float*)d_out;

    // workspace layout (4-byte units)
    float* ws = (float*)d_ws;
    size_t o = 0;
    unsigned short* xlh = (unsigned short*)(ws + o); o += 6400000;  // N*256 bf16
    unsigned short* xrh = (unsigned short*)(ws + o); o += 6400000;  // N*256 bf16
    float*    x1     = ws + o;          o += 3200000;   // N*64 f32
    int*      rowptr = (int*)(ws + o);  o += 50004;     // N+1
    int*      deg    = (int*)(ws + o);  o += 50000;
    int*      cursor = (int*)(ws + o);  o += 50000;
    int*      bsum   = (int*)(ws + o);  o += 256;
    int*      srcs   = (int*)(ws + o);  o += 400000;
    int*      dsts   = (int*)(ws + o);  o += 400000;
    float*    ea_s   = ws + o;          o += 6400000;   // E*16, CSR-sorted
    float*    alpha4 = ws + o;          o += 1600000;   // E*4 logits
    unsigned* amax   = (unsigned*)(ws + o); o += 200000; // N*4 ordered-uint max

    const int GEMM_BLOCKS  = (NN + 31) / 32;    // 1563
    const int SCAN_BLOCKS  = (NN + 255) / 256;  // 196
    const int EDGE_BLOCKS  = (EE + 255) / 256;  // 1563
    const int LOGIT_BLOCKS = 2048;              // 8192 waves, 49 edges each
    const int NODE_BLOCKS  = (NN + 3) / 4;      // 12500

    // ----- CSR build (once; graph identical for both layers) -----
    fill_u32<<<256, 256, 0, stream>>>((unsigned*)deg, 0u, NN);
    hist_k<<<EDGE_BLOCKS, 256, 0, stream>>>(ei, deg);
    scan1_k<<<SCAN_BLOCKS, 256, 0, stream>>>(deg, rowptr, bsum);
    scan2_k<<<1, 256, 0, stream>>>(bsum, SCAN_BLOCKS);
    scan3_k<<<SCAN_BLOCKS, 256, 0, stream>>>(rowptr, bsum, cursor);
    scatter_k<<<EDGE_BLOCKS, 256, 0, stream>>>(ei, cursor, ea, srcs, dsts, ea_s);

    // ----- layer 1 -----
    gemm_node2<<<dim3(GEMM_BLOCKS, 2), 256, 0, stream>>>(h, g1Wl, g1bl, g1Wr, g1br, xlh, xrh);
    fill_u32<<<256, 256, 0, stream>>>(amax, AMAX_INIT, NN * HH);
    edge_logit_k<<<LOGIT_BLOCKS, 256, 0, stream>>>(srcs, dsts, ea_s, g1We, g1att,
                                                   xlh, xrh, alpha4, amax);
    node_agg_k<<<NODE_BLOCKS, 256, 0, stream>>>(rowptr, srcs, alpha4, xlh, amax,
                                                g1bias, ln1g, ln1b, h, x1, out, 0);

    // ----- layer 2 -----
    gemm_node2<<<dim3(GEMM_BLOCKS, 2), 256, 0, stream>>>(x1, g2Wl, g2bl, g2Wr, g2br, xlh, xrh);
    fill_u32<<<256, 256, 0, stream>>>(amax, AMAX_INIT, NN * HH);
    edge_logit_k<<<LOGIT_BLOCKS, 256, 0, stream>>>(srcs, dsts, ea_s, g2We, g2att,
                                                   xlh, xrh, alpha4, amax);
    node_agg_k<<<NODE_BLOCKS, 256, 0, stream>>>(rowptr, srcs, alpha4, xlh, amax,
                                                g2bias, ln2g, ln2b, h, x1, out, 1);
}

// Round 13
// 674.762 us; speedup vs baseline: 1.0096x; 1.0096x over previous
//
#include <hip/hip_runtime.h>
#include <math.h>

// Problem constants (fixed by reference setup_inputs)
#define NN  50000
#define EE  400000
#define DD  64
#define HH  4
#define HC  256      // H * C
#define EDD 16

__device__ __forceinline__ float gelu_exact(float x) {
    return 0.5f * x * (1.0f + erff(x * 0.70710678118654752440f));
}
// fast exp via v_exp_f32: exp(x)=2^(x*log2e). exp2(-inf)=0 preserved.
__device__ __forceinline__ float fast_exp(float x) {
    return __builtin_amdgcn_exp2f(x * 1.44269504088896340736f);
}
// f32 <-> bf16 (RNE)
__device__ __forceinline__ unsigned short f2bf(float f) {
    unsigned u = __float_as_uint(f);
    u += 0x7fffu + ((u >> 16) & 1u);
    return (unsigned short)(u >> 16);
}
__device__ __forceinline__ float bf2f(unsigned short s) {
    return __uint_as_float(((unsigned)s) << 16);
}
// order-preserving float<->uint map for atomicMax on signed floats
__device__ __forceinline__ unsigned fmapu(float f) {
    unsigned u = __float_as_uint(f);
    return (u & 0x80000000u) ? ~u : (u | 0x80000000u);
}
__device__ __forceinline__ float funmapu(unsigned u) {
    u = (u & 0x80000000u) ? (u & 0x7FFFFFFFu) : ~u;
    return __uint_as_float(u);
}
#define AMAX_INIT 0x007FFFFFu   // fmapu(-inf)

// ---------- fills ----------
__global__ void fill_u32(unsigned* __restrict__ p, unsigned v, int n) {
    int i = blockIdx.x * blockDim.x + threadIdx.x;
    int s = gridDim.x * blockDim.x;
    for (; i < n; i += s) p[i] = v;
}

// ---------- CSR build ----------
__global__ void hist_k(const int* __restrict__ ei, int* __restrict__ deg) {
    int e = blockIdx.x * 256 + threadIdx.x;
    if (e < EE) atomicAdd(&deg[ei[EE + e]], 1);
}
__global__ void scan1_k(const int* __restrict__ deg, int* __restrict__ rowptr,
                        int* __restrict__ bsum) {
    __shared__ int s[256];
    int t = threadIdx.x, i = blockIdx.x * 256 + t;
    int v = (i < NN) ? deg[i] : 0;
    s[t] = v; __syncthreads();
    for (int o = 1; o < 256; o <<= 1) {
        int u = (t >= o) ? s[t - o] : 0;
        __syncthreads();
        s[t] += u;
        __syncthreads();
    }
    if (i < NN) rowptr[i] = s[t] - v;
    if (t == 255) bsum[blockIdx.x] = s[255];
}
__global__ void scan2_k(int* __restrict__ bsum, int nb) {
    __shared__ int s[256];
    int t = threadIdx.x;
    int v = (t < nb) ? bsum[t] : 0;
    s[t] = v; __syncthreads();
    for (int o = 1; o < 256; o <<= 1) {
        int u = (t >= o) ? s[t - o] : 0;
        __syncthreads();
        s[t] += u;
        __syncthreads();
    }
    if (t < nb) bsum[t] = s[t] - v;
}
__global__ void scan3_k(int* __restrict__ rowptr, const int* __restrict__ bsum,
                        int* __restrict__ cursor) {
    int i = blockIdx.x * 256 + threadIdx.x;
    if (i < NN) {
        int r = rowptr[i] + bsum[blockIdx.x];
        rowptr[i] = r;
        cursor[i] = r;
    }
    if (i == 0) rowptr[NN] = EE;
}
__global__ void scatter_k(const int* __restrict__ ei, int* __restrict__ cursor,
                          const float* __restrict__ ea,
                          int* __restrict__ srcs, int* __restrict__ dsts,
                          float* __restrict__ ea_s) {
    int e = blockIdx.x * 256 + threadIdx.x;
    if (e >= EE) return;
    int dst = ei[EE + e];
    int pos = atomicAdd(&cursor[dst], 1);
    srcs[pos] = ei[e];
    dsts[pos] = dst;
    const float4* s4 = (const float4*)(ea + (long)e * EDD);
    float4* d4 = (float4*)(ea_s + (long)pos * EDD);
    d4[0] = s4[0]; d4[1] = s4[1]; d4[2] = s4[2]; d4[3] = s4[3];
}

// ---------- node GEMM (dual): Y{l,r}[N,256](bf16) = X[N,64] @ W{l,r} + b ----------
__global__ __launch_bounds__(256) void gemm_node2(
    const float* __restrict__ X,
    const float* __restrict__ Wl, const float* __restrict__ bl,
    const float* __restrict__ Wr, const float* __restrict__ br,
    unsigned short* __restrict__ Yl, unsigned short* __restrict__ Yr)
{
    const int col  = threadIdx.x;
    const int base = blockIdx.x * 32;
    const float* __restrict__ W = blockIdx.y ? Wr : Wl;
    const float* __restrict__ b = blockIdx.y ? br : bl;
    unsigned short* __restrict__ Y = blockIdx.y ? Yr : Yl;

    float wk[64];
#pragma unroll
    for (int k = 0; k < 64; k++) wk[k] = W[k * 256 + col];
    const float bb = b[col];

#pragma unroll 2
    for (int r = 0; r < 32; r++) {
        const int row = base + r;
        const int rr  = (row < NN) ? row : (NN - 1);
        const float* __restrict__ xrow = X + (long)rr * 64;
        float a0 = 0.f, a1 = 0.f, a2 = 0.f, a3 = 0.f;
#pragma unroll
        for (int k = 0; k < 64; k += 4) {
            a0 = fmaf(xrow[k],     wk[k],     a0);
            a1 = fmaf(xrow[k + 1], wk[k + 1], a1);
            a2 = fmaf(xrow[k + 2], wk[k + 2], a2);
            a3 = fmaf(xrow[k + 3], wk[k + 3], a3);
        }
        if (row < NN) Y[(long)row * 256 + col] = f2bf((a0 + a1) + (a2 + a3) + bb);
    }
}

// ---------- phase A: edge logits + fused segment-max ----------
// Lane layout: head h = lane>>4, channel quad (lane&15)*4. xl/xr bf16.
// CSR-ordered slice => consecutive edges usually share dst: xr reloaded only
// on dst change (~8x fewer xr gathers). Per-lane alpha store (no shfl).
// NOTE: do NOT add manual A/B pipelining — wreg(64) + pipeline state spills
// (R9: WRITE_SIZE 9->259 MB, 116->420 us).
__global__ __launch_bounds__(256, 4) void edge_logit_k(
    const int* __restrict__ srcs, const int* __restrict__ dsts,
    const float* __restrict__ ea_s,
    const float* __restrict__ We, const float* __restrict__ att,
    const unsigned short* __restrict__ xlh, const unsigned short* __restrict__ xrh,
    float* __restrict__ alpha4, unsigned* __restrict__ amax)
{
    const int lane = threadIdx.x & 63;
    const int gc   = ((lane >> 4) << 6) + ((lane & 15) << 2);

    float wreg[EDD][4];
#pragma unroll
    for (int k = 0; k < EDD; k++) {
        const float4 w4 = *(const float4*)(We + k * HC + gc);
        wreg[k][0] = w4.x; wreg[k][1] = w4.y; wreg[k][2] = w4.z; wreg[k][3] = w4.w;
    }
#pragma unroll
    for (int k = 0; k < EDD; k++)
#pragma unroll
        for (int j = 0; j < 4; j++) asm volatile("" : "+v"(wreg[k][j]));

    const float4 a4 = *(const float4*)(att + gc);

    const int wid = blockIdx.x * 4 + (threadIdx.x >> 6);
    const int nw  = gridDim.x * 4;
    const int cpw = (EE + nw - 1) / nw;            // 49 <= 64
    const int pbeg = wid * cpw;
    const int pend = (pbeg + cpw < EE) ? (pbeg + cpw) : EE;
    if (pbeg >= pend) return;

    // preload this slice's src/dst into lanes (one coalesced load each)
    const int pl = (pbeg + lane < EE) ? (pbeg + lane) : (EE - 1);
    const int srcv = srcs[pl];
    const int dstv = dsts[pl];

    int prev_dst = -1;
    float xr0 = 0.f, xr1 = 0.f, xr2 = 0.f, xr3 = 0.f;

    for (int p = pbeg; p < pend; p++) {
        const int off = p - pbeg;
        const int src = __builtin_amdgcn_readfirstlane(__shfl(srcv, off, 64));
        const int dst = __builtin_amdgcn_readfirstlane(__shfl(dstv, off, 64));

        if (dst != prev_dst) {   // wave-uniform branch
            const ushort4 xru = *(const ushort4*)(xrh + (long)dst * HC + gc);
            xr0 = bf2f(xru.x); xr1 = bf2f(xru.y);
            xr2 = bf2f(xru.z); xr3 = bf2f(xru.w);
            prev_dst = dst;
        }

        float eav[EDD];
        const float* __restrict__ eap = ea_s + (long)p * EDD;
#pragma unroll
        for (int k = 0; k < EDD; k++) eav[k] = eap[k];

        const ushort4 xlu = *(const ushort4*)(xlh + (long)src * HC + gc);

        float ez0 = 0.f, ez1 = 0.f, ez2 = 0.f, ez3 = 0.f;
#pragma unroll
        for (int k = 0; k < EDD; k++) {
            ez0 = fmaf(eav[k], wreg[k][0], ez0);
            ez1 = fmaf(eav[k], wreg[k][1], ez1);
            ez2 = fmaf(eav[k], wreg[k][2], ez2);
            ez3 = fmaf(eav[k], wreg[k][3], ez3);
        }
        float s0 = bf2f(xlu.x) + xr0 + ez0;
        float s1 = bf2f(xlu.y) + xr1 + ez1;
        float s2 = bf2f(xlu.z) + xr2 + ez2;
        float s3 = bf2f(xlu.w) + xr3 + ez3;
        s0 = (s0 > 0.f) ? s0 : 0.2f * s0;
        s1 = (s1 > 0.f) ? s1 : 0.2f * s1;
        s2 = (s2 > 0.f) ? s2 : 0.2f * s2;
        s3 = (s3 > 0.f) ? s3 : 0.2f * s3;
        float part = fmaf(s0, a4.x, fmaf(s1, a4.y, fmaf(s2, a4.z, s3 * a4.w)));
        part += __shfl_xor(part, 1, 64);
        part += __shfl_xor(part, 2, 64);
        part += __shfl_xor(part, 4, 64);
        part += __shfl_xor(part, 8, 64);

        if ((lane & 15) == 0) {
            // fused segment-max (ordered-uint map); 4 lanes, distinct addrs
            atomicMax(&amax[(long)dst * HH + (lane >> 4)], fmapu(part));
            // per-lane alpha store: 4 lanes write 4 consecutive dwords
            alpha4[(long)p * 4 + (lane >> 4)] = part;
        }
    }
}

// ---------- phase B: per-node softmax + aggregation + LN/GELU ----------
// Pass-1 max comes from amax (fused into phase A). Full 16-edge batches are
// compile-time unrolled so all 16 gathers go in flight together.
__global__ __launch_bounds__(256) void node_agg_k(
    const int* __restrict__ rowptr, const int* __restrict__ srcs,
    const float* __restrict__ alpha4, const unsigned short* __restrict__ xlh,
    const unsigned* __restrict__ amax,
    const float* __restrict__ bias, const float* __restrict__ lng,
    const float* __restrict__ lnb, const float* __restrict__ identity,
    float* __restrict__ x1out, float* __restrict__ outp, int mode)
{
    const int lane = threadIdx.x & 63;
    const int n    = blockIdx.x * 4 + (threadIdx.x >> 6);   // 12500*4 = 50000
    const int h    = lane >> 4;
    const int jj   = lane & 15;
    const int gc   = (h << 6) + (jj << 2);
    const int cb   = jj << 2;

    const int p0 = __builtin_amdgcn_readfirstlane(rowptr[n]);
    const int p1 = __builtin_amdgcn_readfirstlane(rowptr[n + 1]);

    const float mh = funmapu(amax[(long)n * HH + h]);   // per-head max

    float dsum = 0.f;
    float ac0 = 0.f, ac1 = 0.f, ac2 = 0.f, ac3 = 0.f;

    int b = p0;
    // full batches: compile-time unrolled -> 16 independent gathers in flight
    for (; b + 16 <= p1; b += 16) {
        const float a = alpha4[(long)(b + jj) * 4 + h];
        const float w = fast_exp(a - mh);
        dsum += w;
        const int sv = srcs[b + jj];
#pragma unroll
        for (int j = 0; j < 16; j++) {
            const int sj   = __shfl(sv, j, 64);
            const float wj = __shfl(w, (lane & 48) | j, 64);
            const ushort4 xu = *(const ushort4*)(xlh + (long)sj * HC + gc);
            ac0 = fmaf(wj, bf2f(xu.x), ac0);
            ac1 = fmaf(wj, bf2f(xu.y), ac1);
            ac2 = fmaf(wj, bf2f(xu.z), ac2);
            ac3 = fmaf(wj, bf2f(xu.w), ac3);
        }
    }
    // masked tail
    if (b < p1) {
        const int p = b + jj;
        const bool v = (p < p1);
        const int pa = v ? p : (p1 - 1);
        float a = alpha4[(long)pa * 4 + h];
        if (!v) a = -INFINITY;
        const float w = fast_exp(a - mh);          // 0 for invalid lanes
        dsum += w;
        const int sv = srcs[pa];
        const int cnt = p1 - b;
        for (int j = 0; j < cnt; j++) {
            const int sj   = __shfl(sv, j, 64);
            const float wj = __shfl(w, (lane & 48) | j, 64);
            const ushort4 xu = *(const ushort4*)(xlh + (long)sj * HC + gc);
            ac0 = fmaf(wj, bf2f(xu.x), ac0);
            ac1 = fmaf(wj, bf2f(xu.y), ac1);
            ac2 = fmaf(wj, bf2f(xu.z), ac2);
            ac3 = fmaf(wj, bf2f(xu.w), ac3);
        }
    }
    dsum += __shfl_xor(dsum, 1, 64);
    dsum += __shfl_xor(dsum, 2, 64);
    dsum += __shfl_xor(dsum, 4, 64);
    dsum += __shfl_xor(dsum, 8, 64);

    const float inv = 1.0f / (dsum + 1e-16f);
    float v0 = ac0 * inv, v1 = ac1 * inv, v2 = ac2 * inv, v3 = ac3 * inv;

    // head mean across the 4 groups
    v0 += __shfl_xor(v0, 16, 64); v0 += __shfl_xor(v0, 32, 64);
    v1 += __shfl_xor(v1, 16, 64); v1 += __shfl_xor(v1, 32, 64);
    v2 += __shfl_xor(v2, 16, 64); v2 += __shfl_xor(v2, 32, 64);
    v3 += __shfl_xor(v3, 16, 64); v3 += __shfl_xor(v3, 32, 64);

    if (lane < 16) {   // group 0 finishes LN + GELU + store
        const float4 b4 = *(const float4*)(bias + cb);
        v0 = v0 * 0.25f + b4.x;
        v1 = v1 * 0.25f + b4.y;
        v2 = v2 * 0.25f + b4.z;
        v3 = v3 * 0.25f + b4.w;

        float s = (v0 + v1) + (v2 + v3);
        s += __shfl_xor(s, 1, 64); s += __shfl_xor(s, 2, 64);
        s += __shfl_xor(s, 4, 64); s += __shfl_xor(s, 8, 64);
        const float mu = s * (1.0f / 64.0f);
        const float d0 = v0 - mu, d1 = v1 - mu, d2 = v2 - mu, d3 = v3 - mu;
        float q = (d0 * d0 + d1 * d1) + (d2 * d2 + d3 * d3);
        q += __shfl_xor(q, 1, 64); q += __shfl_xor(q, 2, 64);
        q += __shfl_xor(q, 4, 64); q += __shfl_xor(q, 8, 64);
        const float rs = rsqrtf(q * (1.0f / 64.0f) + 1e-5f);

        const float4 g4 = *(const float4*)(lng + cb);
        const float4 c4 = *(const float4*)(lnb + cb);
        float y0 = d0 * rs * g4.x + c4.x;
        float y1 = d1 * rs * g4.y + c4.y;
        float y2 = d2 * rs * g4.z + c4.z;
        float y3 = d3 * rs * g4.w + c4.w;

        if (mode == 0) {
            float4 o;
            o.x = gelu_exact(y0); o.y = gelu_exact(y1);
            o.z = gelu_exact(y2); o.w = gelu_exact(y3);
            *(float4*)(x1out + (long)n * DD + cb) = o;
        } else {
            const float4 id = *(const float4*)(identity + (long)n * DD + cb);
            float4 o;
            o.x = gelu_exact(y0 + id.x); o.y = gelu_exact(y1 + id.y);
            o.z = gelu_exact(y2 + id.z); o.w = gelu_exact(y3 + id.w);
            *(float4*)(outp + (long)n * DD + cb) = o;
        }
    }
}

// ---------- launch ----------
extern "C" void kernel_launch(void* const* d_in, const int* in_sizes, int n_in,
                              void* d_out, int out_size, void* d_ws, size_t ws_size,
                              hipStream_t stream) {
    (void)in_sizes; (void)n_in; (void)out_size; (void)ws_size;

    const float* h     = (const float*)d_in[0];
    const int*   ei    = (const int*)d_in[1];
    const float* ea    = (const float*)d_in[2];
    const float* g1Wl  = (const float*)d_in[3];
    const float* g1bl  = (const float*)d_in[4];
    const float* g1Wr  = (const float*)d_in[5];
    const float* g1br  = (const float*)d_in[6];
    const float* g1We  = (const float*)d_in[7];
    const float* g1att = (const float*)d_in[8];
    const float* g1bias= (const float*)d_in[9];
    const float* ln1g  = (const float*)d_in[10];
    const float* ln1b  = (const float*)d_in[11];
    const float* g2Wl  = (const float*)d_in[12];
    const float* g2bl  = (const float*)d_in[13];
    const float* g2Wr  = (const float*)d_in[14];
    const float* g2br  = (const float*)d_in[15];
    const float* g2We  = (const float*)d_in[16];
    const float* g2att = (const float*)d_in[17];
    const float* g2bias= (const float*)d_in[18];
    const float* ln2g  = (const float*)d_in[19];
    const float* ln2b  = (const float*)d_in[20];

    float* out = (float*)d_out;

    // workspace layout (4-byte units)
    float* ws = (float*)d_ws;
    size_t o = 0;
    unsigned short* xlh = (unsigned short*)(ws + o); o += 6400000;  // N*256 bf16
    unsigned short* xrh = (unsigned short*)(ws + o); o += 6400000;  // N*256 bf16
    float*    x1     = ws + o;          o += 3200000;   // N*64 f32
    int*      rowptr = (int*)(ws + o);  o += 50004;     // N+1
    int*      deg    = (int*)(ws + o);  o += 50000;
    int*      cursor = (int*)(ws + o);  o += 50000;
    int*      bsum   = (int*)(ws + o);  o += 256;
    int*      srcs   = (int*)(ws + o);  o += 400000;
    int*      dsts   = (int*)(ws + o);  o += 400000;
    float*    ea_s   = ws + o;          o += 6400000;   // E*16, CSR-sorted
    float*    alpha4 = ws + o;          o += 1600000;   // E*4 logits
    unsigned* amax   = (unsigned*)(ws + o); o += 200000; // N*4 ordered-uint max

    const int GEMM_BLOCKS  = (NN + 31) / 32;    // 1563
    const int SCAN_BLOCKS  = (NN + 255) / 256;  // 196
    const int EDGE_BLOCKS  = (EE + 255) / 256;  // 1563
    const int LOGIT_BLOCKS = 2048;              // 8192 waves, 49 edges each
    const int NODE_BLOCKS  = (NN + 3) / 4;      // 12500

    // ----- CSR build (once; graph identical for both layers) -----
    fill_u32<<<256, 256, 0, stream>>>((unsigned*)deg, 0u, NN);
    hist_k<<<EDGE_BLOCKS, 256, 0, stream>>>(ei, deg);
    scan1_k<<<SCAN_BLOCKS, 256, 0, stream>>>(deg, rowptr, bsum);
    scan2_k<<<1, 256, 0, stream>>>(bsum, SCAN_BLOCKS);
    scan3_k<<<SCAN_BLOCKS, 256, 0, stream>>>(rowptr, bsum, cursor);
    scatter_k<<<EDGE_BLOCKS, 256, 0, stream>>>(ei, cursor, ea, srcs, dsts, ea_s);

    // ----- layer 1 -----
    gemm_node2<<<dim3(GEMM_BLOCKS, 2), 256, 0, stream>>>(h, g1Wl, g1bl, g1Wr, g1br, xlh, xrh);
    fill_u32<<<256, 256, 0, stream>>>(amax, AMAX_INIT, NN * HH);
    edge_logit_k<<<LOGIT_BLOCKS, 256, 0, stream>>>(srcs, dsts, ea_s, g1We, g1att,
                                                   xlh, xrh, alpha4, amax);
    node_agg_k<<<NODE_BLOCKS, 256, 0, stream>>>(rowptr, srcs, alpha4, xlh, amax,
                                                g1bias, ln1g, ln1b, h, x1, out, 0);

    // ----- layer 2 -----
    gemm_node2<<<dim3(GEMM_BLOCKS, 2), 256, 0, stream>>>(x1, g2Wl, g2bl, g2Wr, g2br, xlh, xrh);
    fill_u32<<<256, 256, 0, stream>>>(amax, AMAX_INIT, NN * HH);
    edge_logit_k<<<LOGIT_BLOCKS, 256, 0, stream>>>(srcs, dsts, ea_s, g2We, g2att,
                                                   xlh, xrh, alpha4, amax);
    node_agg_k<<<NODE_BLOCKS, 256, 0, stream>>>(rowptr, srcs, alpha4, xlh, amax,
                                                g2bias, ln2g, ln2b, h, x1, out, 1);
}